// Round 11
// baseline (10057.682 us; speedup 1.0000x reference)
//
#include <hip/hip_runtime.h>
#include <math.h>

// Problem constants
#define B_  256
#define T_  32
#define S_  128
#define I_  256
#define H_  1024
#define O_  256
#define G4  4096   // 4*H
#define K2  2048   // 2*H

typedef __attribute__((ext_vector_type(8))) short bf16x8;
typedef __attribute__((ext_vector_type(4))) float f32x4;
typedef __attribute__((ext_vector_type(4))) unsigned u32x4;

#define MFMA16(a, b, c) __builtin_amdgcn_mfma_f32_16x16x32_bf16(a, b, c, 0, 0, 0)

__device__ __forceinline__ unsigned short f2bf(float f) {
    unsigned int u = __float_as_uint(f);
    u = (u + 0x7FFFu + ((u >> 16) & 1u)) >> 16;
    return (unsigned short)u;
}
__device__ __forceinline__ float sigm(float x) { return 1.0f / (1.0f + __expf(-x)); }

// L2-coherent flag ops: sc0 = bypass L1, meet at this XCD's L2 (~200 cy).
__device__ __forceinline__ unsigned ldg_l2(const unsigned* p) {
    unsigned r;
    asm volatile("global_load_dword %0, %1, off sc0\n\ts_waitcnt vmcnt(0)"
                 : "=v"(r) : "v"(p) : "memory");
    return r;
}
__device__ __forceinline__ void stg_l2(unsigned* p, unsigned v) {
    asm volatile("global_store_dword %0, %1, off sc0"
                 :: "v"(p), "v"(v) : "memory");
}

// ---------------------------------------------------------------------------
// prep: bf16-convert + gate-reorder weights, convert x (zero t=0), convert
// enc -> encB bf16.  Gate reorder: row r -> n = 4*(r%H)+(r/H).
// Also zeroes flags[256] + claim[8].
// ---------------------------------------------------------------------------
__global__ void prep_kernel(
    const float* __restrict__ x, const float* __restrict__ enc,
    const float* __restrict__ Wih, const float* __restrict__ Whh,
    const float* __restrict__ bih, const float* __restrict__ bhh,
    const float* __restrict__ Wfc,
    unsigned short* __restrict__ WihR, unsigned short* __restrict__ WhhR,
    unsigned short* __restrict__ WfcR, float* __restrict__ biasR,
    unsigned short* __restrict__ xs, unsigned short* __restrict__ encB,
    unsigned* __restrict__ bar)
{
    if (blockIdx.x == 0 && threadIdx.x < 272) bar[threadIdx.x] = 0u;

    const long NWHH = (long)G4 * H_;      // 4,194,304
    const long NWIH = (long)G4 * I_;      // 1,048,576
    const long NWFC = (long)O_ * K2;      //   524,288
    const long NB   = G4;
    const long NX   = (long)B_ * T_ * I_; // 2,097,152
    const long NE   = (long)B_ * S_ * H_; // 33,554,432
    const long total = NWHH + NWIH + NWFC + NB + NX + NE;
    for (long i = (long)blockIdx.x * blockDim.x + threadIdx.x; i < total;
         i += (long)gridDim.x * blockDim.x) {
        long j = i;
        if (j < NE) { encB[j] = f2bf(enc[j]); continue; }
        j -= NE;
        if (j < NWHH) {
            int r = (int)(j >> 10), k = (int)(j & 1023);
            int n = ((r & 1023) << 2) | (r >> 10);
            WhhR[(long)n * H_ + k] = f2bf(Whh[j]);
            continue;
        }
        j -= NWHH;
        if (j < NWIH) {
            int r = (int)(j >> 8), k = (int)(j & 255);
            int n = ((r & 1023) << 2) | (r >> 10);
            WihR[(long)n * I_ + k] = f2bf(Wih[j]);
            continue;
        }
        j -= NWIH;
        if (j < NWFC) { WfcR[j] = f2bf(Wfc[j]); continue; }
        j -= NWFC;
        if (j < NB) {
            int r = (int)j;
            int n = ((r & 1023) << 2) | (r >> 10);
            biasR[n] = bih[r] + bhh[r];
            continue;
        }
        j -= NB;
        {
            int t = (int)((j >> 8) & 31);
            xs[j] = (t == 0) ? (unsigned short)0 : f2bf(x[j]);
        }
    }
}

// ---------------------------------------------------------------------------
// steps: ALL 32 LSTM steps, ONE cooperative launch, INTRA-XCD SYNC ONLY.
// r6/r7/r10 invariant: 3 different h-exchange mechanisms all ~650us because
// every step serially crosses the memside fabric 3-4x (store drain, flag
// land, poll round trip, h fetch) + max-of-64 skew across 8 dies.
// New partition: XCD x (discovered via s_getreg XCC_ID, NOT blockIdx) owns
// batch rows [32x,32x+32); its 32 blocks (1/CU, forced by 150KB LDS) each
// cover 128 gate-cols. Producers+consumers of h share ONE L2:
//  - h: plain stores (write-through to L2), reads via step-rotated address
//    (fresh line -> L1 miss -> own-L2 hit). No sc1, no memside.
//  - flags: sc0 store / sc0-poll (L1 bypass, meet at L2, ~200cy detect).
//  - weights: Whh k<512 in LDS (swizzled); k>=512 + Wih streamed from L2
//    (read-only). t=0 skips phase 2 (h0 = 0).
// 512 threads, 8 waves; wave tile 16m x 32n (wm=wave>>2, wn=wave&3).
// ---------------------------------------------------------------------------
__global__ __launch_bounds__(512, 2) void steps_kernel(
    const unsigned short* __restrict__ xs,   // [B][T][I] bf16
    const unsigned short* __restrict__ WihR, // [4H][I]
    const unsigned short* __restrict__ WhhR, // [4H][H]
    const float* __restrict__ biasR,         // [4H]
    unsigned short* __restrict__ hall,       // [B][T][H] bf16 (exchange+output)
    unsigned* __restrict__ flags,            // [256] (zeroed)
    unsigned* __restrict__ claim)            // [8] per-XCD slot counters
{
    __shared__ unsigned short Wlds[128 * 512]; // 128 KiB: Whh rows n0..n0+128, k<512
    __shared__ float Gs[32 * 132];             // 16.9 KiB gates
    __shared__ unsigned short Hs[32 * 32];     // 2 KiB h-patch gather
    __shared__ int slotS;

    const int tid = threadIdx.x;
    const int lane = tid & 63, wave = tid >> 6;
    const int quad = lane >> 4, l16 = lane & 15;
    const int wm = wave >> 2, wn = wave & 3;

    // --- discover real placement; claim a slot on OUR XCD ---
    unsigned xcc;
    asm("s_getreg_b32 %0, hwreg(HW_REG_XCC_ID)" : "=s"(xcc));
    if (tid == 0) slotS = (int)atomicAdd(claim + xcc, 1u);
    __syncthreads();
    const int slot = slotS & 31;          // 0..31 (mask = OOB insurance)
    const int n0 = slot * 128;            // this block's 128 gate-cols
    const int m0 = (int)xcc * 32;         // this XCD's 32 batch rows
    unsigned* myflag = flags + xcc * 32 + slot;
    const unsigned* gflags = flags + xcc * 32;

    // --- one-time: stage Whh rows [n0,n0+128) k<512 into LDS (swizzled) ---
    for (int i = 0; i < 16; i++) {
        int q = i * 512 + tid;            // 8192 16B-chunks
        int row = q >> 6, kc = q & 63;    // 64 chunks per 512-elem row
        int e = kc * 8;
        int de = row * 512 + (e ^ ((row & 7) << 3));
        *(u32x4*)(Wlds + de) = *(const u32x4*)(WhhR + (long)(n0 + row) * H_ + e);
    }

    // per-lane B rows (2 n-frags) and A row
    int bn[2];
#pragma unroll
    for (int j = 0; j < 2; j++) bn[j] = n0 + wn * 32 + j * 16 + l16;
    const int rr0 = wn * 32 + l16;        // LDS slab row for j=0 (j=1: +16)
    const int am = m0 + wm * 16 + l16;    // A row (global batch row)
    float bj[2];
#pragma unroll
    for (int j = 0; j < 2; j++) bj[j] = biasR[bn[j]];

    // register-resident c: thread handles p = jj*512 + tid (32 rows x 32 u)
    float c_reg[2] = {0.f, 0.f};

    __syncthreads();  // Wlds staged

#pragma unroll 1
    for (int t = 0; t < T_; t++) {
        const f32x4 z = {0.f, 0.f, 0.f, 0.f};
        f32x4 acc[2] = {z, z};

        // phase 1: x_t @ Wih^T (K=256) — h-independent; overlaps the wait.
        {
            const unsigned short* xr = xs + (long)am * T_ * I_ + t * I_ + quad * 8;
            bf16x8 ax[8], bw[8][2];
#pragma unroll
            for (int kk = 0; kk < 8; kk++) {
                ax[kk] = *(const bf16x8*)(xr + kk * 32);
#pragma unroll
                for (int j = 0; j < 2; j++)
                    bw[kk][j] = *(const bf16x8*)(WihR + (long)bn[j] * I_ +
                                                 kk * 32 + quad * 8);
            }
#pragma unroll
            for (int kk = 0; kk < 8; kk++)
#pragma unroll
                for (int j = 0; j < 2; j++)
                    acc[j] = MFMA16(ax[kk], bw[kk][j], acc[j]);
        }

        if (t > 0) {
            // wait: all 32 same-XCD blocks published h_{t-1} (flag >= t)
            if (tid < 32) {
                int spins = 0;
                while (ldg_l2(gflags + tid) < (unsigned)t && spins < (1 << 16)) {
                    __builtin_amdgcn_s_sleep(1);
                    ++spins;
                }
            }
            __syncthreads();

            // phase 2: h_{t-1} @ Whh^T (K=1024), 8 groups of 4 k-chunks,
            // 2-deep pipeline. B: LDS for k<512, L2-global for k>=512.
            const unsigned short* hrow =
                hall + ((long)am * T_ + (t - 1)) * H_ + quad * 8;
            bf16x8 a2[2][4], bb2[2][4][2];
#pragma unroll
            for (int kk = 0; kk < 4; kk++) {
                a2[0][kk] = *(const bf16x8*)(hrow + kk * 32);
#pragma unroll
                for (int j = 0; j < 2; j++) {
                    int r = rr0 + j * 16;
                    int e = (kk * 32 + quad * 8) ^ ((r & 7) << 3);
                    bb2[0][kk][j] = *(const bf16x8*)(Wlds + r * 512 + e);
                }
            }
#pragma unroll
            for (int sc = 0; sc < 8; sc++) {
                const int cur = sc & 1, nxt = cur ^ 1;
                if (sc < 7) {
                    const int kb = (sc + 1) * 4;
#pragma unroll
                    for (int kk = 0; kk < 4; kk++) {
                        a2[nxt][kk] = *(const bf16x8*)(hrow + (kb + kk) * 32);
#pragma unroll
                        for (int j = 0; j < 2; j++) {
                            if (kb + kk < 16) {
                                int r = rr0 + j * 16;
                                int e = ((kb + kk) * 32 + quad * 8) ^
                                        ((r & 7) << 3);
                                bb2[nxt][kk][j] =
                                    *(const bf16x8*)(Wlds + r * 512 + e);
                            } else {
                                bb2[nxt][kk][j] = *(const bf16x8*)(
                                    WhhR + (long)bn[j] * H_ + (kb + kk) * 32 +
                                    quad * 8);
                            }
                        }
                    }
                }
#pragma unroll
                for (int kk = 0; kk < 4; kk++)
#pragma unroll
                    for (int j = 0; j < 2; j++)
                        acc[j] = MFMA16(a2[cur][kk], bb2[cur][kk][j], acc[j]);
            }
        }

        // gates + bias -> Gs (row = wm*16 + quad*4 + r, col = wn*32 + j*16 + l16)
#pragma unroll
        for (int j = 0; j < 2; j++)
#pragma unroll
            for (int r = 0; r < 4; r++)
                Gs[(wm * 16 + quad * 4 + r) * 132 + wn * 32 + j * 16 + l16] =
                    acc[j][r] + bj[j];
        __syncthreads();

        // fused cell: 32 rows x 32 units; c register-resident; h -> Hs
#pragma unroll
        for (int jj = 0; jj < 2; jj++) {
            int p = jj * 512 + tid;
            int row = p >> 5, u = p & 31;
            float gi = Gs[row * 132 + u * 4 + 0];
            float gf = Gs[row * 132 + u * 4 + 1];
            float gg = Gs[row * 132 + u * 4 + 2];
            float go = Gs[row * 132 + u * 4 + 3];
            float ii = sigm(gi), ff = sigm(gf), g3 = tanhf(gg), oo = sigm(go);
            float cn = ff * c_reg[jj] + ii * g3;
            float hh = oo * tanhf(cn);
            c_reg[jj] = cn;
            Hs[row * 32 + u] = f2bf(hh);
        }
        __syncthreads();

        // h patch -> hall[b][t][slot*32 .. +32) : 128 x 16B PLAIN stores
        // (write-through to this XCD's L2; consumers are all on this XCD)
        if (tid < 128) {
            int row = tid >> 2, seg = tid & 3;
            u32x4 v = *(const u32x4*)(Hs + row * 32 + seg * 8);
            *(u32x4*)(hall + ((long)(m0 + row) * T_ + t) * H_ +
                      slot * 32 + seg * 8) = v;
        }

        // arrive: h stores at L2, then set own flag (sc0, L2-visible)
        if (t < T_ - 1) {
            asm volatile("s_waitcnt vmcnt(0)" ::: "memory");
            __syncthreads();   // all waves drained; Gs/Hs safe to reuse
            if (tid == 0) stg_l2(myflag, (unsigned)(t + 1));
        }
    }
}

// ---------------------------------------------------------------------------
// scores: per-b S = hall[b](32x1024) @ encB[b]^T (128x1024)^T, fused softmax.
// ---------------------------------------------------------------------------
__global__ __launch_bounds__(256) void scores_kernel(
    const unsigned short* __restrict__ hall, // [B][T][H]
    const unsigned short* __restrict__ encB, // [B][S][H]
    float* __restrict__ probs,               // [B][T][S]
    unsigned short* __restrict__ PB)         // [B][T][S] bf16
{
    __shared__ float Sc[32 * 132];

    const int tid = threadIdx.x;
    const int lane = tid & 63, wave = tid >> 6;
    const int quad = lane >> 4, l16 = lane & 15;
    const int b = blockIdx.x;
    const int nw = wave;  // 4 waves x 32 s-cols

    const unsigned short* pa0 = hall + ((long)b * T_ + l16) * H_ + quad * 8;
    const unsigned short* pa1 = hall + ((long)b * T_ + 16 + l16) * H_ + quad * 8;
    const unsigned short* pb0 = encB + ((long)b * S_ + nw * 32 + l16) * H_ + quad * 8;
    const unsigned short* pb1 = pb0 + 16 * H_;

    const f32x4 z = {0.f, 0.f, 0.f, 0.f};
    f32x4 acc00 = z, acc01 = z, acc10 = z, acc11 = z;

#pragma unroll 4
    for (int k0 = 0; k0 < H_; k0 += 32) {
        bf16x8 a0 = *(const bf16x8*)(pa0 + k0);
        bf16x8 a1 = *(const bf16x8*)(pa1 + k0);
        bf16x8 b0 = *(const bf16x8*)(pb0 + k0);
        bf16x8 b1 = *(const bf16x8*)(pb1 + k0);
        acc00 = MFMA16(a0, b0, acc00);
        acc01 = MFMA16(a0, b1, acc01);
        acc10 = MFMA16(a1, b0, acc10);
        acc11 = MFMA16(a1, b1, acc11);
    }
#pragma unroll
    for (int r = 0; r < 4; r++) {
        int row0 = quad * 4 + r;
        int col0 = nw * 32 + l16;
        Sc[row0 * 132 + col0]            = acc00[r];
        Sc[row0 * 132 + col0 + 16]       = acc01[r];
        Sc[(row0 + 16) * 132 + col0]      = acc10[r];
        Sc[(row0 + 16) * 132 + col0 + 16] = acc11[r];
    }
    __syncthreads();
    // softmax: wave handles 8 rows; 128 cols = 2 per lane
    for (int r = 0; r < 8; r++) {
        int row = wave * 8 + r;
        float v0 = Sc[row * 132 + lane];
        float v1 = Sc[row * 132 + 64 + lane];
        float mx = fmaxf(v0, v1);
#pragma unroll
        for (int off = 32; off > 0; off >>= 1) mx = fmaxf(mx, __shfl_xor(mx, off));
        float e0 = __expf(v0 - mx), e1 = __expf(v1 - mx);
        float s = e0 + e1;
#pragma unroll
        for (int off = 32; off > 0; off >>= 1) s += __shfl_xor(s, off);
        float inv = 1.0f / s;
        float p0 = e0 * inv, p1 = e1 * inv;
        long o = ((long)b * T_ + row) * S_;
        probs[o + lane] = p0;
        probs[o + 64 + lane] = p1;
        PB[o + lane] = f2bf(p0);
        PB[o + 64 + lane] = f2bf(p1);
    }
}

// ---------------------------------------------------------------------------
// ctx: C[b] = P[b](32x128) @ encB[b](128x1024) -> CTX bf16. grid(B, 4).
// ---------------------------------------------------------------------------
__global__ __launch_bounds__(256) void ctx_kernel(
    const unsigned short* __restrict__ encB, // [B][S][H]
    const unsigned short* __restrict__ PB,   // [B][T][S]
    unsigned short* __restrict__ ctxo)       // [B*T][H] bf16
{
    __shared__ unsigned short Es[S_ * 256];  // 64 KB

    const int tid = threadIdx.x;
    const int lane = tid & 63, wave = tid >> 6;
    const int quad = lane >> 4, l16 = lane & 15;
    const int b = blockIdx.x;
    const int h0 = blockIdx.y * 256;

    // stage encB[b][:, h0:h0+256] -> LDS [s][256]
    for (int i = tid; i < S_ * 32; i += 256) {
        int s = i >> 5, hc = (i & 31) * 8;
        *(u32x4*)(Es + s * 256 + hc) =
            *(const u32x4*)(encB + ((long)b * S_ + s) * H_ + h0 + hc);
    }
    // A fragments (P rows t, k = s), direct loads
    bf16x8 a[2][4];
#pragma unroll
    for (int i = 0; i < 2; i++)
#pragma unroll
        for (int ks = 0; ks < 4; ks++)
            a[i][ks] = *(const bf16x8*)(PB + ((long)b * T_ + i * 16 + l16) * S_ +
                                        ks * 32 + quad * 8);
    __syncthreads();

    f32x4 acc[2][4];
    const f32x4 z = {0.f, 0.f, 0.f, 0.f};
#pragma unroll
    for (int i = 0; i < 2; i++)
#pragma unroll
        for (int j = 0; j < 4; j++) acc[i][j] = z;

    const int cw = wave * 64;
#pragma unroll
    for (int ks = 0; ks < 4; ks++) {
        const int kb = ks * 32 + quad * 8;
#pragma unroll
        for (int j = 0; j < 4; j++) {
            const int col = cw + j * 16 + l16;
            bf16x8 bb;
#pragma unroll
            for (int e = 0; e < 8; e++) bb[e] = (short)Es[(kb + e) * 256 + col];
            acc[0][j] = MFMA16(a[0][ks], bb, acc[0][j]);
            acc[1][j] = MFMA16(a[1][ks], bb, acc[1][j]);
        }
    }
#pragma unroll
    for (int i = 0; i < 2; i++)
#pragma unroll
        for (int j = 0; j < 4; j++)
#pragma unroll
            for (int r = 0; r < 4; r++) {
                int row = i * 16 + quad * 4 + r;
                int col = h0 + cw + j * 16 + l16;
                ctxo[((long)b * T_ + row) * H_ + col] = f2bf(acc[i][j][r]);
            }
}

// ---------------------------------------------------------------------------
// fc: out = [ctx | h](8192x2048) @ WfcR^T (256x2048) + bfc. Tile 64x128.
// ---------------------------------------------------------------------------
__global__ __launch_bounds__(256) void fc_kernel(
    const unsigned short* __restrict__ ctxo, // [B*T][H]
    const unsigned short* __restrict__ hall, // [B*T][H]
    const unsigned short* __restrict__ WfcR,
    const float* __restrict__ bfc,
    float* __restrict__ out)
{
    __shared__ __align__(16) unsigned short As[64 * 40];
    __shared__ __align__(16) unsigned short Bs[128 * 40];

    const int tid = threadIdx.x;
    const int lane = tid & 63, wave = tid >> 6;
    const int wm = wave >> 1, wn = wave & 1;
    const int quad = lane >> 4, l16 = lane & 15;
    const int n0 = blockIdx.x * 128, m0 = blockIdx.y * 64;

    const int arow = tid >> 2, akc = (tid & 3) * 8;
    const int brow = tid >> 1, bkc = (tid & 1) * 16;

    f32x4 acc[2][4];
    const f32x4 z = {0.f, 0.f, 0.f, 0.f};
#pragma unroll
    for (int i = 0; i < 2; i++)
#pragma unroll
        for (int j = 0; j < 4; j++) acc[i][j] = z;

    for (int k0 = 0; k0 < K2; k0 += 32) {
        const unsigned short* asrc = (k0 < H_)
            ? ctxo + (long)(m0 + arow) * H_ + k0 + akc
            : hall + (long)(m0 + arow) * H_ + (k0 - H_) + akc;
        *(u32x4*)(As + arow * 40 + akc) = *(const u32x4*)asrc;
        const unsigned short* src = WfcR + (long)(n0 + brow) * K2 + k0 + bkc;
        *(u32x4*)(Bs + brow * 40 + bkc)     = *(const u32x4*)src;
        *(u32x4*)(Bs + brow * 40 + bkc + 8) = *(const u32x4*)(src + 8);
        __syncthreads();
        bf16x8 a0 = *(const bf16x8*)(As + (wm * 32 + l16) * 40 + quad * 8);
        bf16x8 a1 = *(const bf16x8*)(As + (wm * 32 + 16 + l16) * 40 + quad * 8);
#pragma unroll
        for (int j = 0; j < 4; j++) {
            bf16x8 bb = *(const bf16x8*)(Bs + (wn * 64 + j * 16 + l16) * 40 + quad * 8);
            acc[0][j] = MFMA16(a0, bb, acc[0][j]);
            acc[1][j] = MFMA16(a1, bb, acc[1][j]);
        }
        __syncthreads();
    }
#pragma unroll
    for (int i = 0; i < 2; i++)
#pragma unroll
        for (int j = 0; j < 4; j++)
#pragma unroll
            for (int r = 0; r < 4; r++) {
                int row = m0 + wm * 32 + i * 16 + quad * 4 + r;
                int col = n0 + wn * 64 + j * 16 + l16;
                out[(long)row * O_ + col] = acc[i][j][r] + bfc[col];
            }
}

// ---------------------------------------------------------------------------
extern "C" void kernel_launch(void* const* d_in, const int* in_sizes, int n_in,
                              void* d_out, int out_size, void* d_ws, size_t ws_size,
                              hipStream_t stream) {
    const float* x   = (const float*)d_in[0];
    const float* enc = (const float*)d_in[1];
    const float* Wih = (const float*)d_in[2];
    const float* Whh = (const float*)d_in[3];
    const float* bih = (const float*)d_in[4];
    const float* bhh = (const float*)d_in[5];
    const float* Wfc = (const float*)d_in[6];
    const float* bfc = (const float*)d_in[7];
    float* out = (float*)d_out;

    char* ws = (char*)d_ws;
    // workspace layout (bytes); total ~120.6 MB
    unsigned short* WIHR = (unsigned short*)(ws + 0);           //  2,097,152
    unsigned short* WHHR = (unsigned short*)(ws + 2097152);     //  8,388,608
    unsigned short* WFCR = (unsigned short*)(ws + 10485760);    //  1,048,576
    float*          BIAS = (float*)         (ws + 11534336);    //     16,384
    unsigned short* XS   = (unsigned short*)(ws + 11550720);    //  4,194,304
    unsigned*       BAR  = (unsigned*)      (ws + 16793600);    // flags[256]
    unsigned*       CLM  = (unsigned*)      (ws + 16794624);    // claim[8]
    unsigned short* HALL = (unsigned short*)(ws + 17842176);    // 16,777,216
    unsigned short* ENCB = (unsigned short*)(ws + 34619392);    // 67,108,864
    unsigned short* PB   = (unsigned short*)(ws + 101728256);   //  2,097,152
    unsigned short* CTX  = (unsigned short*)(ws + 103825408);   // 16,777,216

    prep_kernel<<<8192, 256, 0, stream>>>(x, enc, Wih, Whh, bih, bhh, Wfc,
                                          WIHR, WHHR, WFCR, BIAS, XS, ENCB,
                                          BAR);

    // all 32 LSTM steps in one persistent cooperative launch (512 threads)
    {
        void* args[] = {(void*)&XS, (void*)&WIHR, (void*)&WHHR, (void*)&BIAS,
                        (void*)&HALL, (void*)&BAR, (void*)&CLM};
        (void)hipLaunchCooperativeKernel(reinterpret_cast<void*>(steps_kernel),
                                         dim3(256), dim3(512), args, 0, stream);
    }

    scores_kernel<<<B_, 256, 0, stream>>>(HALL, ENCB,
                                          out + (long)B_ * T_ * O_, PB);
    ctx_kernel<<<dim3(B_, 4), 256, 0, stream>>>(ENCB, PB, CTX);
    fc_kernel<<<dim3(2, 128), 256, 0, stream>>>(CTX, HALL, WFCR, bfc, out);
}

// Round 12
// 967.774 us; speedup vs baseline: 10.3926x; 10.3926x over previous
//
#include <hip/hip_runtime.h>
#include <math.h>

// Problem constants
#define B_  256
#define T_  32
#define S_  128
#define I_  256
#define H_  1024
#define O_  256
#define G4  4096   // 4*H
#define K2  2048   // 2*H

typedef __attribute__((ext_vector_type(8))) short bf16x8;
typedef __attribute__((ext_vector_type(4))) float f32x4;
typedef __attribute__((ext_vector_type(4))) unsigned u32x4;

#define MFMA16(a, b, c) __builtin_amdgcn_mfma_f32_16x16x32_bf16(a, b, c, 0, 0, 0)

__device__ __forceinline__ unsigned short f2bf(float f) {
    unsigned int u = __float_as_uint(f);
    u = (u + 0x7FFFu + ((u >> 16) & 1u)) >> 16;
    return (unsigned short)u;
}
__device__ __forceinline__ float sigm(float x) { return 1.0f / (1.0f + __expf(-x)); }

// memside-coherent 16B store (write-through; no L2 allocation).
// Operand must be ext_vector_type (struct uint4 breaks asm "v" constraint).
__device__ __forceinline__ void stg_sys128(unsigned short* p, u32x4 v) {
    asm volatile("global_store_dwordx4 %0, %1, off sc0 sc1"
                 :: "v"(p), "v"(v) : "memory");
}
// flag ops: memside-coherent dword access; load waits internally.
__device__ __forceinline__ unsigned ldg_flag(const unsigned* p) {
    unsigned r;
    asm volatile("global_load_dword %0, %1, off sc0 sc1\n\ts_waitcnt vmcnt(0)"
                 : "=v"(r) : "v"(p) : "memory");
    return r;
}
__device__ __forceinline__ void stg_flag(unsigned* p, unsigned v) {
    asm volatile("global_store_dword %0, %1, off sc0 sc1"
                 :: "v"(p), "v"(v) : "memory");
}

// ---------------------------------------------------------------------------
// prep: VECTORIZED x4 bf16-convert + gate-reorder weights, convert x (zero
// t=0), enc -> encB, zero h0.  Gate reorder: row r -> n = 4*(r%H)+(r/H).
// Also zeroes the 256-entry flag array.
// ---------------------------------------------------------------------------
__global__ void prep_kernel(
    const float* __restrict__ x, const float* __restrict__ enc,
    const float* __restrict__ Wih, const float* __restrict__ Whh,
    const float* __restrict__ bih, const float* __restrict__ bhh,
    const float* __restrict__ Wfc,
    unsigned short* __restrict__ WihR, unsigned short* __restrict__ WhhR,
    unsigned short* __restrict__ WfcR, float* __restrict__ biasR,
    unsigned short* __restrict__ xs, unsigned short* __restrict__ encB,
    unsigned short* __restrict__ h0,
    unsigned* __restrict__ bar)
{
    if (blockIdx.x == 0 && threadIdx.x < 256) bar[threadIdx.x] = 0u;

    const long NE4   = (long)B_ * S_ * H_ / 4;  // 8,388,608
    const long NWHH4 = (long)G4 * H_ / 4;       // 1,048,576
    const long NWIH4 = (long)G4 * I_ / 4;       //   262,144
    const long NWFC4 = (long)O_ * K2 / 4;       //   131,072
    const long NX4   = (long)B_ * T_ * I_ / 4;  //   524,288
    const long NH4   = (long)B_ * H_ / 4;       //    65,536
    const long NB    = G4;
    const long total = NE4 + NWHH4 + NWIH4 + NWFC4 + NX4 + NH4 + NB;
    for (long i = (long)blockIdx.x * blockDim.x + threadIdx.x; i < total;
         i += (long)gridDim.x * blockDim.x) {
        long j = i;
        if (j < NE4) {
            float4 v = *(const float4*)(enc + j * 4);
            ushort4 o = {f2bf(v.x), f2bf(v.y), f2bf(v.z), f2bf(v.w)};
            *(ushort4*)(encB + j * 4) = o;
            continue;
        }
        j -= NE4;
        if (j < NWHH4) {
            long e = j * 4;
            int r = (int)(e >> 10), k = (int)(e & 1023);
            int n = ((r & 1023) << 2) | (r >> 10);
            float4 v = *(const float4*)(Whh + e);
            ushort4 o = {f2bf(v.x), f2bf(v.y), f2bf(v.z), f2bf(v.w)};
            *(ushort4*)(WhhR + (long)n * H_ + k) = o;
            continue;
        }
        j -= NWHH4;
        if (j < NWIH4) {
            long e = j * 4;
            int r = (int)(e >> 8), k = (int)(e & 255);
            int n = ((r & 1023) << 2) | (r >> 10);
            float4 v = *(const float4*)(Wih + e);
            ushort4 o = {f2bf(v.x), f2bf(v.y), f2bf(v.z), f2bf(v.w)};
            *(ushort4*)(WihR + (long)n * I_ + k) = o;
            continue;
        }
        j -= NWIH4;
        if (j < NWFC4) {
            long e = j * 4;
            float4 v = *(const float4*)(Wfc + e);
            ushort4 o = {f2bf(v.x), f2bf(v.y), f2bf(v.z), f2bf(v.w)};
            *(ushort4*)(WfcR + e) = o;
            continue;
        }
        j -= NWFC4;
        if (j < NX4) {
            long e = j * 4;
            int t = (int)((e >> 8) & 31);
            ushort4 o = {0, 0, 0, 0};
            if (t != 0) {
                float4 v = *(const float4*)(x + e);
                o.x = f2bf(v.x); o.y = f2bf(v.y);
                o.z = f2bf(v.z); o.w = f2bf(v.w);
            }
            *(ushort4*)(xs + e) = o;
            continue;
        }
        j -= NX4;
        if (j < NH4) {
            ushort4 zz = {0, 0, 0, 0};
            *(ushort4*)(h0 + j * 4) = zz;
            continue;
        }
        j -= NH4;
        {
            int r = (int)j;
            int n = ((r & 1023) << 2) | (r >> 10);
            biasR[n] = bih[r] + bhh[r];
        }
    }
}

// ---------------------------------------------------------------------------
// steps: r10-PROVEN kernel (641us, stable in live+profiled runs), reverted
// from r11's intra-XCD scheme (585us profiled but 10ms live — placement/
// state-fragile under graph replay). Sole change vs r10: phase 2 skipped at
// t=0 (h0 = 0 contributes exactly +0.0 -> bitwise identical).
// grid 256 blocks x 512 threads (8 waves, 2/SIMD), 1 block/CU.
// Block tile 64m x 64n; wave tile 32m x 16n. Whh slab (128 KiB) in LDS
// (XOR-swizzled), Wih in registers, c register-resident.
// h exchange: address rotation — h_t written ONCE to hall[b][t][:] via
// sc0 sc1 write-through (16B stores gathered in LDS); h_{t-1} read with
// normal cached loads (fresh 2KB-aligned rows -> compulsory miss -> fresh).
// Flag-array barrier: 4 independent mt-groups of 64 blocks.
// ---------------------------------------------------------------------------
__global__ __launch_bounds__(512, 2) void steps_kernel(
    const unsigned short* __restrict__ xs,   // [B][T][I] bf16
    const unsigned short* __restrict__ WihR, // [4H][I]
    const unsigned short* __restrict__ WhhR, // [4H][H]
    const float* __restrict__ biasR,         // [4H]
    const unsigned short* __restrict__ h0b,  // [B][H] bf16 (zeroed, unused math-wise)
    unsigned short* __restrict__ hall,       // [B][T][H] bf16 (exchange+output)
    unsigned* __restrict__ bar)              // flags[256] (zeroed)
{
    __shared__ unsigned short Wlds[64 * 1024];  // 128 KiB weight slab
    __shared__ float Gs[64 * 68];               // 17408 B gates
    __shared__ unsigned short Hs[64 * 16];      // 2 KiB h-patch gather

    const int tid = threadIdx.x;
    const int lane = tid & 63, wave = tid >> 6;
    const int quad = lane >> 4, l16 = lane & 15;
    const int wm = wave >> 2, wn = wave & 3;

    // XCD-aware persistent mapping: 8 n-tiles x 4 m-tiles per XCD
    const int id = blockIdx.x;
    const int xcd = id & 7, slot = id >> 3;   // slot 0..31
    const int nt = slot >> 2, mt = slot & 3;
    const int n0 = (xcd * 8 + nt) * 64;
    const int m0 = mt * 64;

    // barrier addressing: group = mt (the 64 blocks producing rows m0..m0+63)
    unsigned* myflag = bar + mt * 64 + xcd * 8 + nt;
    const unsigned* gflags = bar + mt * 64;

    // ---- one-time: stage Whh slab rows [n0, n0+64) into LDS (swizzled) ----
    for (int i = 0; i < 16; i++) {
        int q = i * 512 + tid;                // 8192 16B-chunks
        int row = q >> 7, kc = q & 127;       // 128 chunks per row
        int e = kc * 8;
        int de = row * 1024 + (e ^ ((row & 7) << 3));
        *(u32x4*)(Wlds + de) = *(const u32x4*)(WhhR + (long)(n0 + row) * H_ + e);
    }

    // Wih fragments in registers (16 n-rows x 256 k per wave = 32 VGPRs)
    const int nw = n0 + wn * 16 + l16;        // this lane's weight/gate col
    bf16x8 bwx[8];
    {
        const unsigned short* px = WihR + (long)nw * I_ + quad * 8;
#pragma unroll
        for (int kk = 0; kk < 8; kk++) bwx[kk] = *(const bf16x8*)(px + kk * 32);
    }
    const float bj = biasR[nw];

    // B ds_read base for this lane
    const unsigned short* bbase = Wlds + (wn * 16 + l16) * 1024;
    const int swz = (l16 & 7) << 3;

    // A row indices (2 m-fragments of 16 rows each)
    int arow[2];
    const unsigned short* xrow[2];
#pragma unroll
    for (int i = 0; i < 2; i++) {
        arow[i] = m0 + wm * 32 + i * 16 + l16;
        xrow[i] = xs + (long)arow[i] * T_ * I_ + quad * 8;
    }

    // register-resident c: thread handles items p = j*512 + tid
    float c_reg[2] = {0.f, 0.f};

    __syncthreads();  // Wlds staged

#pragma unroll 1
    for (int t = 0; t < T_; t++) {
        const f32x4 z = {0.f, 0.f, 0.f, 0.f};
        f32x4 acc[2] = {z, z};

        // phase 1: x_t @ Wih^T (K = 256) — independent of h; overlaps barrier
        {
            bf16x8 a[8][2];
#pragma unroll
            for (int kk = 0; kk < 8; kk++)
#pragma unroll
                for (int i = 0; i < 2; i++)
                    a[kk][i] = *(const bf16x8*)(xrow[i] + (long)t * I_ + kk * 32);
#pragma unroll
            for (int kk = 0; kk < 8; kk++)
#pragma unroll
                for (int i = 0; i < 2; i++)
                    acc[i] = MFMA16(a[kk][i], bwx[kk], acc[i]);
        }

        if (t > 0) {
            // wait: all 64 same-mt blocks published h_{t-1} (flag >= t)
            if (tid < 64) {
                int spins = 0;
                while (ldg_flag(gflags + tid) < (unsigned)t &&
                       spins < (1 << 20)) {
                    __builtin_amdgcn_s_sleep(1);
                    ++spins;
                }
            }
            __syncthreads();

            // h_{t-1}: step-rotated hall row (normal cached loads)
            const unsigned short* hb = hall + (long)(t - 1) * H_;
            const long hstr = (long)T_ * H_;
            const unsigned short* rp0 = hb + (long)arow[0] * hstr + quad * 8;
            const unsigned short* rp1 = hb + (long)arow[1] * hstr + quad * 8;

            // phase 2: h_prev @ Whh^T (K = 1024) — 8 sub-chunks, 2-deep pipe
            bf16x8 aa[2][4][2];   // [buf][kk][i], static-indexed via unroll
#pragma unroll
            for (int kk = 0; kk < 4; kk++) {
                aa[0][kk][0] = *(const bf16x8*)(rp0 + kk * 32);
                aa[0][kk][1] = *(const bf16x8*)(rp1 + kk * 32);
            }
#pragma unroll
            for (int sc = 0; sc < 8; sc++) {
                const int cur = sc & 1, nxt = cur ^ 1;
                if (sc < 7) {
                    const int kb = (sc + 1) * 4;
#pragma unroll
                    for (int kk = 0; kk < 4; kk++) {
                        aa[nxt][kk][0] = *(const bf16x8*)(rp0 + (kb + kk) * 32);
                        aa[nxt][kk][1] = *(const bf16x8*)(rp1 + (kb + kk) * 32);
                    }
                }
#pragma unroll
                for (int kk = 0; kk < 4; kk++) {
                    int e = ((sc * 4 + kk) * 32 + quad * 8) ^ swz;
                    bf16x8 bb = *(const bf16x8*)(bbase + e);
                    acc[0] = MFMA16(aa[cur][kk][0], bb, acc[0]);
                    acc[1] = MFMA16(aa[cur][kk][1], bb, acc[1]);
                }
            }
        }

        // gates + bias -> LDS (row = wm*32 + i*16 + quad*4 + r, col = wn*16+l16)
#pragma unroll
        for (int i = 0; i < 2; i++)
#pragma unroll
            for (int r = 0; r < 4; r++)
                Gs[(wm * 32 + i * 16 + quad * 4 + r) * 68 + wn * 16 + l16] =
                    acc[i][r] + bj;
        __syncthreads();

        // fused cell: 64 rows x 16 units; c register-resident; h -> Hs
#pragma unroll
        for (int j = 0; j < 2; j++) {
            int p = j * 512 + tid;
            int row = p >> 4, u = p & 15;
            float gi = Gs[row * 68 + u * 4 + 0];
            float gf = Gs[row * 68 + u * 4 + 1];
            float gg = Gs[row * 68 + u * 4 + 2];
            float go = Gs[row * 68 + u * 4 + 3];
            float ii = sigm(gi), ff = sigm(gf), g3 = tanhf(gg), oo = sigm(go);
            float cn = ff * c_reg[j] + ii * g3;
            float hh = oo * tanhf(cn);
            c_reg[j] = cn;
            Hs[row * 16 + u] = f2bf(hh);
        }
        __syncthreads();

        // h patch -> hall[b][t][:] as 128 x 16B memside write-through stores
        if (tid < 128) {
            int row = tid >> 1, half = tid & 1;
            u32x4 v = *(const u32x4*)(Hs + row * 16 + half * 8);
            unsigned short* dst = hall +
                ((long)(m0 + row) * T_ + t) * H_ + (n0 >> 2) + half * 8;
            stg_sys128(dst, v);
        }

        // arrive: h stores acked at coherence point, then set own flag
        if (t < T_ - 1) {
            asm volatile("s_waitcnt vmcnt(0)" ::: "memory");
            __syncthreads();   // all waves drained; also protects Gs/Hs
            if (tid == 0) stg_flag(myflag, (unsigned)(t + 1));
        }
    }
}

// ---------------------------------------------------------------------------
// attn: FUSED scores+softmax+ctx. grid(B), 256 threads.
// Phase A: S = hall[b](32x1024) @ encB[b]^T, softmax -> probs (global) and
// P bf16 -> LDS (no PB global round-trip). Phase B: ctx = P @ encB[b] in
// 4 h-chunks of 256, encB staged to LDS (L2-hot from phase A's pass).
// Identical math to the old scores_kernel + ctx_kernel pair.
// ---------------------------------------------------------------------------
__global__ __launch_bounds__(256) void attn_kernel(
    const unsigned short* __restrict__ hall, // [B][T][H]
    const unsigned short* __restrict__ encB, // [B][S][H]
    float* __restrict__ probs,               // [B][T][S]
    unsigned short* __restrict__ ctxo)       // [B*T][H] bf16
{
    __shared__ float Sc[32 * 132];           // 16896 B
    __shared__ unsigned short Ps[32 * 128];  //  8192 B
    __shared__ unsigned short Es[S_ * 256];  // 65536 B  (total ~90.6 KB)

    const int tid = threadIdx.x;
    const int lane = tid & 63, wave = tid >> 6;
    const int quad = lane >> 4, l16 = lane & 15;
    const int b = blockIdx.x;
    const int nw = wave;  // 4 waves x 32 s-cols

    // ---- phase A: scores ----
    const unsigned short* pa0 = hall + ((long)b * T_ + l16) * H_ + quad * 8;
    const unsigned short* pa1 = hall + ((long)b * T_ + 16 + l16) * H_ + quad * 8;
    const unsigned short* pb0 = encB + ((long)b * S_ + nw * 32 + l16) * H_ + quad * 8;
    const unsigned short* pb1 = pb0 + 16 * H_;

    const f32x4 z = {0.f, 0.f, 0.f, 0.f};
    f32x4 acc00 = z, acc01 = z, acc10 = z, acc11 = z;

#pragma unroll 4
    for (int k0 = 0; k0 < H_; k0 += 32) {
        bf16x8 a0 = *(const bf16x8*)(pa0 + k0);
        bf16x8 a1 = *(const bf16x8*)(pa1 + k0);
        bf16x8 b0 = *(const bf16x8*)(pb0 + k0);
        bf16x8 b1 = *(const bf16x8*)(pb1 + k0);
        acc00 = MFMA16(a0, b0, acc00);
        acc01 = MFMA16(a0, b1, acc01);
        acc10 = MFMA16(a1, b0, acc10);
        acc11 = MFMA16(a1, b1, acc11);
    }
#pragma unroll
    for (int r = 0; r < 4; r++) {
        int row0 = quad * 4 + r;
        int col0 = nw * 32 + l16;
        Sc[row0 * 132 + col0]            = acc00[r];
        Sc[row0 * 132 + col0 + 16]       = acc01[r];
        Sc[(row0 + 16) * 132 + col0]      = acc10[r];
        Sc[(row0 + 16) * 132 + col0 + 16] = acc11[r];
    }
    __syncthreads();
    // softmax: wave handles 8 rows; 128 cols = 2 per lane; P -> Ps (LDS)
    for (int r = 0; r < 8; r++) {
        int row = wave * 8 + r;
        float v0 = Sc[row * 132 + lane];
        float v1 = Sc[row * 132 + 64 + lane];
        float mx = fmaxf(v0, v1);
#pragma unroll
        for (int off = 32; off > 0; off >>= 1) mx = fmaxf(mx, __shfl_xor(mx, off));
        float e0 = __expf(v0 - mx), e1 = __expf(v1 - mx);
        float s = e0 + e1;
#pragma unroll
        for (int off = 32; off > 0; off >>= 1) s += __shfl_xor(s, off);
        float inv = 1.0f / s;
        float p0 = e0 * inv, p1 = e1 * inv;
        long o = ((long)b * T_ + row) * S_;
        probs[o + lane] = p0;
        probs[o + 64 + lane] = p1;
        Ps[row * 128 + lane] = f2bf(p0);
        Ps[row * 128 + 64 + lane] = f2bf(p1);
    }
    __syncthreads();

    // A fragments for ctx (P rows t, k = s) from LDS
    bf16x8 a[2][4];
#pragma unroll
    for (int i = 0; i < 2; i++)
#pragma unroll
        for (int ks = 0; ks < 4; ks++)
            a[i][ks] = *(const bf16x8*)(Ps + (i * 16 + l16) * 128 +
                                        ks * 32 + quad * 8);

    // ---- phase B: ctx in 4 h-chunks of 256 ----
    const int cw = wave * 64;
    for (int hc = 0; hc < 4; hc++) {
        if (hc) __syncthreads();  // Es reuse guard
        // stage encB[b][:, hc*256 .. +256) -> Es [s][256]  (L2-hot)
        for (int i = tid; i < S_ * 32; i += 256) {
            int s = i >> 5, hcc = (i & 31) * 8;
            *(u32x4*)(Es + s * 256 + hcc) =
                *(const u32x4*)(encB + ((long)b * S_ + s) * H_ + hc * 256 + hcc);
        }
        __syncthreads();

        f32x4 acc[2][4];
#pragma unroll
        for (int i = 0; i < 2; i++)
#pragma unroll
            for (int j = 0; j < 4; j++) acc[i][j] = z;

#pragma unroll
        for (int ks = 0; ks < 4; ks++) {
            const int kb = ks * 32 + quad * 8;
#pragma unroll
            for (int j = 0; j < 4; j++) {
                const int col = cw + j * 16 + l16;
                bf16x8 bb;
#pragma unroll
                for (int e = 0; e < 8; e++) bb[e] = (short)Es[(kb + e) * 256 + col];
                acc[0][j] = MFMA16(a[0][ks], bb, acc[0][j]);
                acc[1][j] = MFMA16(a[1][ks], bb, acc[1][j]);
            }
        }
#pragma unroll
        for (int i = 0; i < 2; i++)
#pragma unroll
            for (int j = 0; j < 4; j++)
#pragma unroll
                for (int r = 0; r < 4; r++) {
                    int row = i * 16 + quad * 4 + r;
                    int col = hc * 256 + cw + j * 16 + l16;
                    ctxo[((long)b * T_ + row) * H_ + col] = f2bf(acc[i][j][r]);
                }
    }
}

// ---------------------------------------------------------------------------
// fc: out = [ctx | h](8192x2048) @ WfcR^T (256x2048) + bfc. Tile 64x128.
// ---------------------------------------------------------------------------
__global__ __launch_bounds__(256) void fc_kernel(
    const unsigned short* __restrict__ ctxo, // [B*T][H]
    const unsigned short* __restrict__ hall, // [B*T][H]
    const unsigned short* __restrict__ WfcR,
    const float* __restrict__ bfc,
    float* __restrict__ out)
{
    __shared__ __align__(16) unsigned short As[64 * 40];
    __shared__ __align__(16) unsigned short Bs[128 * 40];

    const int tid = threadIdx.x;
    const int lane = tid & 63, wave = tid >> 6;
    const int wm = wave >> 1, wn = wave & 1;
    const int quad = lane >> 4, l16 = lane & 15;
    const int n0 = blockIdx.x * 128, m0 = blockIdx.y * 64;

    const int arow = tid >> 2, akc = (tid & 3) * 8;
    const int brow = tid >> 1, bkc = (tid & 1) * 16;

    f32x4 acc[2][4];
    const f32x4 z = {0.f, 0.f, 0.f, 0.f};
#pragma unroll
    for (int i = 0; i < 2; i++)
#pragma unroll
        for (int j = 0; j < 4; j++) acc[i][j] = z;

    for (int k0 = 0; k0 < K2; k0 += 32) {
        const unsigned short* asrc = (k0 < H_)
            ? ctxo + (long)(m0 + arow) * H_ + k0 + akc
            : hall + (long)(m0 + arow) * H_ + (k0 - H_) + akc;
        *(u32x4*)(As + arow * 40 + akc) = *(const u32x4*)asrc;
        const unsigned short* src = WfcR + (long)(n0 + brow) * K2 + k0 + bkc;
        *(u32x4*)(Bs + brow * 40 + bkc)     = *(const u32x4*)src;
        *(u32x4*)(Bs + brow * 40 + bkc + 8) = *(const u32x4*)(src + 8);
        __syncthreads();
        bf16x8 a0 = *(const bf16x8*)(As + (wm * 32 + l16) * 40 + quad * 8);
        bf16x8 a1 = *(const bf16x8*)(As + (wm * 32 + 16 + l16) * 40 + quad * 8);
#pragma unroll
        for (int j = 0; j < 4; j++) {
            bf16x8 bb = *(const bf16x8*)(Bs + (wn * 64 + j * 16 + l16) * 40 + quad * 8);
            acc[0][j] = MFMA16(a0, bb, acc[0][j]);
            acc[1][j] = MFMA16(a1, bb, acc[1][j]);
        }
        __syncthreads();
    }
#pragma unroll
    for (int i = 0; i < 2; i++)
#pragma unroll
        for (int j = 0; j < 4; j++)
#pragma unroll
            for (int r = 0; r < 4; r++) {
                int row = m0 + wm * 32 + i * 16 + quad * 4 + r;
                int col = n0 + wn * 64 + j * 16 + l16;
                out[(long)row * O_ + col] = acc[i][j][r] + bfc[col];
            }
}

// ---------------------------------------------------------------------------
extern "C" void kernel_launch(void* const* d_in, const int* in_sizes, int n_in,
                              void* d_out, int out_size, void* d_ws, size_t ws_size,
                              hipStream_t stream) {
    const float* x   = (const float*)d_in[0];
    const float* enc = (const float*)d_in[1];
    const float* Wih = (const float*)d_in[2];
    const float* Whh = (const float*)d_in[3];
    const float* bih = (const float*)d_in[4];
    const float* bhh = (const float*)d_in[5];
    const float* Wfc = (const float*)d_in[6];
    const float* bfc = (const float*)d_in[7];
    float* out = (float*)d_out;

    char* ws = (char*)d_ws;
    // workspace layout (bytes); total ~120.6 MB
    unsigned short* WIHR = (unsigned short*)(ws + 0);           //  2,097,152
    unsigned short* WHHR = (unsigned short*)(ws + 2097152);     //  8,388,608
    unsigned short* WFCR = (unsigned short*)(ws + 10485760);    //  1,048,576
    float*          BIAS = (float*)         (ws + 11534336);    //     16,384
    unsigned short* XS   = (unsigned short*)(ws + 11550720);    //  4,194,304
    unsigned short* H0   = (unsigned short*)(ws + 15745024);    //    524,288
    unsigned*       BAR  = (unsigned*)      (ws + 16793600);    // flags[256]
    unsigned short* HALL = (unsigned short*)(ws + 17842176);    // 16,777,216
    unsigned short* ENCB = (unsigned short*)(ws + 34619392);    // 67,108,864
    unsigned short* CTX  = (unsigned short*)(ws + 103825408);   // 16,777,216

    prep_kernel<<<4096, 256, 0, stream>>>(x, enc, Wih, Whh, bih, bhh, Wfc,
                                          WIHR, WHHR, WFCR, BIAS, XS, ENCB,
                                          H0, BAR);

    // all 32 LSTM steps in one persistent cooperative launch (512 threads)
    {
        void* args[] = {(void*)&XS, (void*)&WIHR, (void*)&WHHR, (void*)&BIAS,
                        (void*)&H0, (void*)&HALL, (void*)&BAR};
        (void)hipLaunchCooperativeKernel(reinterpret_cast<void*>(steps_kernel),
                                         dim3(256), dim3(512), args, 0, stream);
    }

    attn_kernel<<<B_, 256, 0, stream>>>(HALL, ENCB,
                                        out + (long)B_ * T_ * O_, CTX);
    fc_kernel<<<dim3(2, 128), 256, 0, stream>>>(CTX, HALL, WFCR, bfc, out);
}